// Round 12
// baseline (27.239 us; speedup 1.0000x reference)
//
#include <hip/hip_runtime.h>
#include <stdint.h>

#define NQ 8
#define DIM 256
#define BSZ 32768
#define NOPS 20

typedef float v2f __attribute__((ext_vector_type(2)));

// ================= compile-time replication of np.random.RandomState(0) =================

struct COps { int kind[NOPS]; int w0[NOPS]; int w1[NOPS]; };

struct CMT {
  uint32_t mt[624]; int pos;
  constexpr CMT(uint32_t seed) : mt{}, pos(624) {
    for (int i = 0; i < 624; ++i) {
      mt[i] = seed;
      seed = 1812433253u * (seed ^ (seed >> 30)) + (uint32_t)(i + 1);
    }
  }
  constexpr uint32_t next32() {
    if (pos >= 624) {
      for (int i = 0; i < 624; ++i) {
        uint32_t y = (mt[i] & 0x80000000u) | (mt[(i + 1) % 624] & 0x7fffffffu);
        mt[i] = mt[(i + 397) % 624] ^ (y >> 1) ^ ((y & 1u) ? 0x9908b0dfu : 0u);
      }
      pos = 0;
    }
    uint32_t y = mt[pos++];
    y ^= y >> 11; y ^= (y << 7) & 0x9d2c5680u; y ^= (y << 15) & 0xefc60000u; y ^= y >> 18;
    return y;
  }
  constexpr uint32_t interval(uint32_t mx) {  // legacy masked rejection, [0, mx]
    if (mx == 0u) return 0u;
    uint32_t mask = mx;
    mask |= mask >> 1; mask |= mask >> 2; mask |= mask >> 4; mask |= mask >> 8; mask |= mask >> 16;
    uint32_t v = next32() & mask;
    while (v > mx) v = next32() & mask;
    return v;
  }
};

constexpr COps decode_ops() {
  COps o{}; CMT r(0u);
  for (int k = 0; k < NOPS; ++k) {
    const uint32_t kind = r.interval(3u);            // randint(4)
    o.kind[k] = (int)kind;
    if (kind == 3u) {                                // choice(8,2,False) == permutation(8)[:2]
      int perm[NQ] = {0,1,2,3,4,5,6,7};
      for (int i = NQ - 1; i >= 1; --i) {
        const uint32_t j = r.interval((uint32_t)i);
        const int t = perm[i]; perm[i] = perm[(int)j]; perm[(int)j] = t;
      }
      o.w0[k] = perm[0]; o.w1[k] = perm[1];
    } else {
      o.w0[k] = (int)r.interval(7u);                 // randint(8)
      o.w1[k] = -1;
    }
  }
  return o;
}

constexpr COps OPS = decode_ops();

// ================= device helpers =================

// raw-DPP cross-lane read (within 16-lane row)
template<int CTRL>
__device__ __forceinline__ float lanedpp(float v) {
  return __builtin_bit_cast(float,
    __builtin_amdgcn_update_dpp(0, __builtin_bit_cast(int, v), CTRL, 0xF, 0xF, true));
}

// XOR exchange within 16-lane groups — ALL DPP, zero LDS:
//   xor1 = quad_perm(1,0,3,2) 0xB1 ; xor2 = quad_perm(2,3,0,1) 0x4E
//   xor8 = row_ror:8 0x128 ; xor4 = row_half_mirror(xor7) 0x141 + quad_perm(3,2,1,0)(xor3) 0x1B
template<int MASK>
__device__ __forceinline__ float lanexf(float v) {
  if constexpr (MASK == 1)      return lanedpp<0xB1>(v);
  else if constexpr (MASK == 2) return lanedpp<0x4E>(v);
  else if constexpr (MASK == 8) return lanedpp<0x128>(v);
  else                          return lanedpp<0x1B>(lanedpp<0x141>(v));
}

template<int MASK>
__device__ __forceinline__ v2f lanex2(v2f v) {
  v2f r; r.x = lanexf<MASK>(v.x); r.y = lanexf<MASK>(v.y); return r;
}

__device__ __forceinline__ v2f vswap(v2f v) { return __builtin_shufflevector(v, v, 1, 0); }
__device__ __forceinline__ v2f vsplat(float s) { v2f r = {s, s}; return r; }

// Layout: amplitude d = (j<<4)|l ; wire w -> mask m = 1<<(7-w) in d.
// m >= 16: in-lane pair (j0, j0|m>>4) ; m < 16: cross-lane DPP.
// Tan-form gates: U = c(I + t G); c deferred into observable scale C^2.

template<int W>
__device__ __forceinline__ void g_rx_t(v2f (&v)[16], int l, float t) {
  constexpr int m = 1 << (7 - W);
  const v2f tpm = {t, -t};
  if constexpr (m >= 16) {
    constexpr int M = m >> 4;
    #pragma unroll
    for (int j0 = 0; j0 < 16; ++j0) if ((j0 & M) == 0) {
      const int j1 = j0 | M;
      v2f a = v[j0], b = v[j1];
      v[j0] = a + tpm * vswap(b);
      v[j1] = b + tpm * vswap(a);
    }
  } else {
    #pragma unroll
    for (int j = 0; j < 16; ++j) {
      v2f x = lanex2<m>(v[j]);
      v[j] = v[j] + tpm * vswap(x);
    }
  }
}

template<int W>
__device__ __forceinline__ void g_ry_t(v2f (&v)[16], int l, float t) {
  constexpr int m = 1 << (7 - W);
  if constexpr (m >= 16) {
    constexpr int M = m >> 4;
    const v2f vtn = vsplat(-t), vtp = vsplat(t);
    #pragma unroll
    for (int j0 = 0; j0 < 16; ++j0) if ((j0 & M) == 0) {
      const int j1 = j0 | M;
      v2f a = v[j0], b = v[j1];
      v[j0] = a + vtn * b;
      v[j1] = b + vtp * a;
    }
  } else {
    const v2f ts = vsplat((l & m) ? t : -t);
    #pragma unroll
    for (int j = 0; j < 16; ++j) {
      v2f x = lanex2<m>(v[j]);
      v[j] = v[j] + ts * x;
    }
  }
}

template<int W>
__device__ __forceinline__ void g_rz_t(v2f (&v)[16], int l, float t) {
  constexpr int m = 1 << (7 - W);
  if constexpr (m >= 16) {
    constexpr int M = m >> 4;
    const v2f tpm = {t, -t};
    #pragma unroll
    for (int j = 0; j < 16; ++j) {
      v2f sw = vswap(v[j]);
      if ((j & M) == 0) v[j] = v[j] + tpm * sw;
      else              v[j] = v[j] - tpm * sw;
    }
  } else {
    const v2f ts = (l & m) ? (v2f){-t, t} : (v2f){t, -t};
    #pragma unroll
    for (int j = 0; j < 16; ++j) v[j] = v[j] + ts * vswap(v[j]);
  }
}

template<int WC, int WT>
__device__ __forceinline__ void g_cnot(v2f (&v)[16], int l) {
  constexpr int mc = 1 << (7 - WC);
  constexpr int mt = 1 << (7 - WT);
  if constexpr (mt >= 16) {           // in-lane target
    constexpr int M = mt >> 4;
    if constexpr (mc >= 16) {         // j-control: pure register rename
      constexpr int MC = mc >> 4;
      #pragma unroll
      for (int j0 = 0; j0 < 16; ++j0) if ((j0 & M) == 0 && (j0 & MC) != 0) {
        const int j1 = j0 | M;
        v2f t = v[j0]; v[j0] = v[j1]; v[j1] = t;
      }
    } else {                          // lane-control: per-lane select
      const bool bit = (l & mc) != 0;
      #pragma unroll
      for (int j0 = 0; j0 < 16; ++j0) if ((j0 & M) == 0) {
        const int j1 = j0 | M;
        v2f a = v[j0], b = v[j1];
        v[j0] = bit ? b : a;
        v[j1] = bit ? a : b;
      }
    }
  } else {                            // cross-lane target
    if constexpr (mc >= 16) {         // j-control: exchange only controlled j's
      constexpr int MC = mc >> 4;
      #pragma unroll
      for (int j = 0; j < 16; ++j) if (j & MC) v[j] = lanex2<mt>(v[j]);
    } else if constexpr ((mc == 8 || mc == 4) && mt != 4) {
      // lane-control on a bank boundary: bank-masked DPP, no cndmask.
      constexpr int BM   = (mc == 8) ? 0xC : 0xA;
      constexpr int ctrl = (mt == 1) ? 0xB1 : (mt == 2) ? 0x4E : 0x128;
      #pragma unroll
      for (int j = 0; j < 16; ++j) {
        int ir = __builtin_bit_cast(int, v[j].x);
        int ii = __builtin_bit_cast(int, v[j].y);
        ir = __builtin_amdgcn_update_dpp(ir, ir, ctrl, 0xF, BM, false);
        ii = __builtin_amdgcn_update_dpp(ii, ii, ctrl, 0xF, BM, false);
        v[j].x = __builtin_bit_cast(float, ir);
        v[j].y = __builtin_bit_cast(float, ii);
      }
    } else {                          // lane-control, general
      const bool bit = (l & mc) != 0;
      #pragma unroll
      for (int j = 0; j < 16; ++j) {
        v2f x = lanex2<mt>(v[j]);
        v[j] = bit ? x : v[j];
      }
    }
  }
}

// fully unrolled, compile-time op sequence; cacc accumulates the deferred cos factors
template<int K>
__device__ __forceinline__ void apply_ops(v2f (&v)[16], int l, const float* __restrict__ rl, float& cacc) {
  if constexpr (K < NOPS) {
    constexpr int kind = OPS.kind[K];
    if constexpr (kind == 3) {
      g_cnot<OPS.w0[K], OPS.w1[K]>(v, l);
    } else {
      float sn, cs;
      __sincosf(0.5f * rl[K], &sn, &cs);
      const float t = sn * __builtin_amdgcn_rcpf(cs);
      cacc *= cs;
      if constexpr      (kind == 0) g_rx_t<OPS.w0[K]>(v, l, t);
      else if constexpr (kind == 1) g_ry_t<OPS.w0[K]>(v, l, t);
      else                          g_rz_t<OPS.w0[K]>(v, l, t);
    }
    apply_ops<K + 1>(v, l, rl, cacc);
  }
}

// ---- observable: M = nx*X + ny*Y + nz*Z per wire (final RX/RY folded in) ----

template<int M>
__device__ __forceinline__ float xy_inlane(const v2f (&v)[16], float tnx, float tny) {
  v2f aRe = {0.f, 0.f}, aIm = {0.f, 0.f};
  #pragma unroll
  for (int j0 = 0; j0 < 16; ++j0) if ((j0 & M) == 0) {
    const int j1 = j0 | M;
    aRe += v[j0] * v[j1];
    aIm += v[j0] * vswap(v[j1]);
  }
  return tnx * (aRe.x + aRe.y) + tny * (aIm.x - aIm.y);
}

template<int MASK>
__device__ __forceinline__ float xy_cross(const v2f (&v)[16], int l, float nx, float ny) {
  v2f aRe = {0.f, 0.f}, aIm = {0.f, 0.f};
  #pragma unroll
  for (int j = 0; j < 16; ++j) {
    v2f x = lanex2<MASK>(v[j]);
    aRe += v[j] * x;
    aIm += v[j] * vswap(x);
  }
  const float nys = (l & MASK) ? -ny : ny;
  return nx * (aRe.x + aRe.y) + nys * (aIm.x - aIm.y);  // both lanes summed -> factor 2
}

// product-state init for one sample
__device__ __forceinline__ void init_state(v2f (&v)[16], const float* __restrict__ xrow, int l) {
  const float4* xp = reinterpret_cast<const float4*>(xrow);
  const float4 xa = xp[0], xb = xp[1];
  float sw[8], cw[8];
  __sincosf(0.5f * xa.x, &sw[0], &cw[0]);
  __sincosf(0.5f * xa.y, &sw[1], &cw[1]);
  __sincosf(0.5f * xa.z, &sw[2], &cw[2]);
  __sincosf(0.5f * xa.w, &sw[3], &cw[3]);
  __sincosf(0.5f * xb.x, &sw[4], &cw[4]);
  __sincosf(0.5f * xb.y, &sw[5], &cw[5]);
  __sincosf(0.5f * xb.z, &sw[6], &cw[6]);
  __sincosf(0.5f * xb.w, &sw[7], &cw[7]);

  const float pl = ((l & 8) ? sw[4] : cw[4]) * ((l & 4) ? sw[5] : cw[5]) *
                   ((l & 2) ? sw[6] : cw[6]) * ((l & 1) ? sw[7] : cw[7]);
  const float p01[4] = {cw[0]*cw[1], cw[0]*sw[1], sw[0]*cw[1], sw[0]*sw[1]};
  const float p23[4] = {cw[2]*cw[3], cw[2]*sw[3], sw[2]*cw[3], sw[2]*sw[3]};
  const float p01l[4] = {p01[0]*pl, p01[1]*pl, p01[2]*pl, p01[3]*pl};
  #pragma unroll
  for (int j = 0; j < 16; ++j) { v[j].x = p01l[j >> 2] * p23[j & 3]; v[j].y = 0.f; }
}

__global__ __launch_bounds__(256)
void qcnn_kernel(const float* __restrict__ x, const float* __restrict__ rl,
                 const float* __restrict__ thx, const float* __restrict__ thy,
                 float* __restrict__ out)
{
  const int tid = blockIdx.x * blockDim.x + threadIdx.x;
  const int b = tid >> 4;
  const int l = tid & 15;

  v2f v[16];
  init_state(v, x + (size_t)b * 8, l);

  // ---- 20 compile-time gates (tan form, deferred cos product) ----
  float cacc = 1.0f;
  apply_ops<0>(v, l, rl, cacc);
  const float C2 = cacc * cacc;

  // ---- folded final RX/RY layer: observable direction, scaled by C^2 ----
  float sxf, cxf, syf, cyf;
  __sincosf(thx[0], &sxf, &cxf);
  __sincosf(thy[0], &syf, &cyf);
  const float nx = -syf * C2, ny = cyf * sxf * C2, nz = cyf * cxf * C2;
  const float tnx = 2.f * nx, tny = 2.f * ny;

  // ---- Z parts: STREAMING signed |amp|^2 sums (R4 form — q consumed immediately,
  //      5 live v2f accumulators; avoids R9/R10's q[16] register-pressure spike) ----
  v2f P2 = {0,0}, A0v = {0,0}, A1v = {0,0}, A2v = {0,0}, A3v = {0,0};
  #pragma unroll
  for (int j = 0; j < 16; ++j) {
    const v2f q = v[j] * v[j];
    P2 += q;
    if (j & 8) A0v -= q; else A0v += q;
    if (j & 4) A1v -= q; else A1v += q;
    if (j & 2) A2v -= q; else A2v += q;
    if (j & 1) A3v -= q; else A3v += q;
  }
  const float P  = P2.x + P2.y;
  const float A0 = A0v.x + A0v.y, A1 = A1v.x + A1v.y;
  const float A2 = A2v.x + A2v.y, A3 = A3v.x + A3v.y;

  float t0 = fmaf(nz, A0, xy_inlane<8>(v, tnx, tny));
  float t1 = fmaf(nz, A1, xy_inlane<4>(v, tnx, tny));
  float t2 = fmaf(nz, A2, xy_inlane<2>(v, tnx, tny));
  float t3 = fmaf(nz, A3, xy_inlane<1>(v, tnx, tny));
  float t4 = fmaf(nz, (l & 8) ? -P : P, xy_cross<8>(v, l, nx, ny));
  float t5 = fmaf(nz, (l & 4) ? -P : P, xy_cross<4>(v, l, nx, ny));
  float t6 = fmaf(nz, (l & 2) ? -P : P, xy_cross<2>(v, l, nx, ny));
  float t7 = fmaf(nz, (l & 1) ? -P : P, xy_cross<1>(v, l, nx, ny));

  // 16-lane full reduce via {qp_swap1, qp_swap2, ror:4, ror:8} — single-DPP steps
  // (verified R9/R10); after step2 each quad holds its 4-sum, rotations merge all quads.
  #define RED_STEP(CTRL) \
    t0 += lanedpp<CTRL>(t0); t1 += lanedpp<CTRL>(t1); t2 += lanedpp<CTRL>(t2); t3 += lanedpp<CTRL>(t3); \
    t4 += lanedpp<CTRL>(t4); t5 += lanedpp<CTRL>(t5); t6 += lanedpp<CTRL>(t6); t7 += lanedpp<CTRL>(t7);
  RED_STEP(0xB1) RED_STEP(0x4E) RED_STEP(0x124) RED_STEP(0x128)
  #undef RED_STEP

  if (l == 0) {
    float4* o = reinterpret_cast<float4*>(out + (size_t)b * 8);
    const float4 o0 = {t0, t1, t2, t3};
    const float4 o1 = {t4, t5, t6, t7};
    o[0] = o0; o[1] = o1;
  }
}

// ================= host =================

extern "C" void kernel_launch(void* const* d_in, const int* in_sizes, int n_in,
                              void* d_out, int out_size, void* d_ws, size_t ws_size,
                              hipStream_t stream) {
  const float* x   = (const float*)d_in[0];
  const float* rl  = (const float*)d_in[1];
  const float* thx = (const float*)d_in[2];
  const float* thy = (const float*)d_in[3];
  float* out = (float*)d_out;

  const int threads = 256;                  // 4 waves, 16 samples per block
  const int blocks = BSZ / (threads / 16);  // 2048
  qcnn_kernel<<<blocks, threads, 0, stream>>>(x, rl, thx, thy, out);
}

// Round 13
// 27.169 us; speedup vs baseline: 1.0026x; 1.0026x over previous
//
#include <hip/hip_runtime.h>
#include <stdint.h>

#define NQ 8
#define DIM 256
#define BSZ 32768
#define NOPS 20

typedef float v2f __attribute__((ext_vector_type(2)));

// ================= compile-time replication of np.random.RandomState(0) =================

struct COps { int kind[NOPS]; int w0[NOPS]; int w1[NOPS]; };

struct CMT {
  uint32_t mt[624]; int pos;
  constexpr CMT(uint32_t seed) : mt{}, pos(624) {
    for (int i = 0; i < 624; ++i) {
      mt[i] = seed;
      seed = 1812433253u * (seed ^ (seed >> 30)) + (uint32_t)(i + 1);
    }
  }
  constexpr uint32_t next32() {
    if (pos >= 624) {
      for (int i = 0; i < 624; ++i) {
        uint32_t y = (mt[i] & 0x80000000u) | (mt[(i + 1) % 624] & 0x7fffffffu);
        mt[i] = mt[(i + 397) % 624] ^ (y >> 1) ^ ((y & 1u) ? 0x9908b0dfu : 0u);
      }
      pos = 0;
    }
    uint32_t y = mt[pos++];
    y ^= y >> 11; y ^= (y << 7) & 0x9d2c5680u; y ^= (y << 15) & 0xefc60000u; y ^= y >> 18;
    return y;
  }
  constexpr uint32_t interval(uint32_t mx) {  // legacy masked rejection, [0, mx]
    if (mx == 0u) return 0u;
    uint32_t mask = mx;
    mask |= mask >> 1; mask |= mask >> 2; mask |= mask >> 4; mask |= mask >> 8; mask |= mask >> 16;
    uint32_t v = next32() & mask;
    while (v > mx) v = next32() & mask;
    return v;
  }
};

constexpr COps decode_ops() {
  COps o{}; CMT r(0u);
  for (int k = 0; k < NOPS; ++k) {
    const uint32_t kind = r.interval(3u);            // randint(4)
    o.kind[k] = (int)kind;
    if (kind == 3u) {                                // choice(8,2,False) == permutation(8)[:2]
      int perm[NQ] = {0,1,2,3,4,5,6,7};
      for (int i = NQ - 1; i >= 1; --i) {
        const uint32_t j = r.interval((uint32_t)i);
        const int t = perm[i]; perm[i] = perm[(int)j]; perm[(int)j] = t;
      }
      o.w0[k] = perm[0]; o.w1[k] = perm[1];
    } else {
      o.w0[k] = (int)r.interval(7u);                 // randint(8)
      o.w1[k] = -1;
    }
  }
  return o;
}

constexpr COps OPS = decode_ops();

// ================= device helpers =================

// raw-DPP cross-lane read (within 16-lane row)
template<int CTRL>
__device__ __forceinline__ float lanedpp(float v) {
  return __builtin_bit_cast(float,
    __builtin_amdgcn_update_dpp(0, __builtin_bit_cast(int, v), CTRL, 0xF, 0xF, true));
}

// XOR exchange within 16-lane groups — ALL DPP, zero LDS:
//   xor1 = quad_perm(1,0,3,2) 0xB1 ; xor2 = quad_perm(2,3,0,1) 0x4E
//   xor8 = row_ror:8 0x128 ; xor4 = row_half_mirror(xor7) 0x141 + quad_perm(3,2,1,0)(xor3) 0x1B
template<int MASK>
__device__ __forceinline__ float lanexf(float v) {
  if constexpr (MASK == 1)      return lanedpp<0xB1>(v);
  else if constexpr (MASK == 2) return lanedpp<0x4E>(v);
  else if constexpr (MASK == 8) return lanedpp<0x128>(v);
  else                          return lanedpp<0x1B>(lanedpp<0x141>(v));
}

template<int MASK>
__device__ __forceinline__ v2f lanex2(v2f v) {
  v2f r; r.x = lanexf<MASK>(v.x); r.y = lanexf<MASK>(v.y); return r;
}

__device__ __forceinline__ v2f vswap(v2f v) { return __builtin_shufflevector(v, v, 1, 0); }
__device__ __forceinline__ v2f vsplat(float s) { v2f r = {s, s}; return r; }

// Layout: amplitude d = (j<<4)|l ; wire w -> mask m = 1<<(7-w) in d.
// m >= 16: in-lane pair (j0, j0|m>>4) ; m < 16: cross-lane DPP.
// Tan-form gates: U = c(I + t G); c deferred into observable scale C^2.

template<int W>
__device__ __forceinline__ void g_rx_t(v2f (&v)[16], int l, float t) {
  constexpr int m = 1 << (7 - W);
  const v2f tpm = {t, -t};
  if constexpr (m >= 16) {
    constexpr int M = m >> 4;
    #pragma unroll
    for (int j0 = 0; j0 < 16; ++j0) if ((j0 & M) == 0) {
      const int j1 = j0 | M;
      v2f a = v[j0], b = v[j1];
      v[j0] = a + tpm * vswap(b);
      v[j1] = b + tpm * vswap(a);
    }
  } else {
    #pragma unroll
    for (int j = 0; j < 16; ++j) {
      v2f x = lanex2<m>(v[j]);
      v[j] = v[j] + tpm * vswap(x);
    }
  }
}

template<int W>
__device__ __forceinline__ void g_ry_t(v2f (&v)[16], int l, float t) {
  constexpr int m = 1 << (7 - W);
  if constexpr (m >= 16) {
    constexpr int M = m >> 4;
    const v2f vtn = vsplat(-t), vtp = vsplat(t);
    #pragma unroll
    for (int j0 = 0; j0 < 16; ++j0) if ((j0 & M) == 0) {
      const int j1 = j0 | M;
      v2f a = v[j0], b = v[j1];
      v[j0] = a + vtn * b;
      v[j1] = b + vtp * a;
    }
  } else {
    const v2f ts = vsplat((l & m) ? t : -t);
    #pragma unroll
    for (int j = 0; j < 16; ++j) {
      v2f x = lanex2<m>(v[j]);
      v[j] = v[j] + ts * x;
    }
  }
}

template<int W>
__device__ __forceinline__ void g_rz_t(v2f (&v)[16], int l, float t) {
  constexpr int m = 1 << (7 - W);
  if constexpr (m >= 16) {
    constexpr int M = m >> 4;
    const v2f tpm = {t, -t};
    #pragma unroll
    for (int j = 0; j < 16; ++j) {
      v2f sw = vswap(v[j]);
      if ((j & M) == 0) v[j] = v[j] + tpm * sw;
      else              v[j] = v[j] - tpm * sw;
    }
  } else {
    const v2f ts = (l & m) ? (v2f){-t, t} : (v2f){t, -t};
    #pragma unroll
    for (int j = 0; j < 16; ++j) v[j] = v[j] + ts * vswap(v[j]);
  }
}

template<int WC, int WT>
__device__ __forceinline__ void g_cnot(v2f (&v)[16], int l) {
  constexpr int mc = 1 << (7 - WC);
  constexpr int mt = 1 << (7 - WT);
  if constexpr (mt >= 16) {           // in-lane target
    constexpr int M = mt >> 4;
    if constexpr (mc >= 16) {         // j-control: pure register rename
      constexpr int MC = mc >> 4;
      #pragma unroll
      for (int j0 = 0; j0 < 16; ++j0) if ((j0 & M) == 0 && (j0 & MC) != 0) {
        const int j1 = j0 | M;
        v2f t = v[j0]; v[j0] = v[j1]; v[j1] = t;
      }
    } else {                          // lane-control: per-lane select
      const bool bit = (l & mc) != 0;
      #pragma unroll
      for (int j0 = 0; j0 < 16; ++j0) if ((j0 & M) == 0) {
        const int j1 = j0 | M;
        v2f a = v[j0], b = v[j1];
        v[j0] = bit ? b : a;
        v[j1] = bit ? a : b;
      }
    }
  } else {                            // cross-lane target
    if constexpr (mc >= 16) {         // j-control: exchange only controlled j's
      constexpr int MC = mc >> 4;
      #pragma unroll
      for (int j = 0; j < 16; ++j) if (j & MC) v[j] = lanex2<mt>(v[j]);
    } else if constexpr ((mc == 8 || mc == 4) && mt != 4) {
      // lane-control on a bank boundary: bank-masked DPP, no cndmask.
      constexpr int BM   = (mc == 8) ? 0xC : 0xA;
      constexpr int ctrl = (mt == 1) ? 0xB1 : (mt == 2) ? 0x4E : 0x128;
      #pragma unroll
      for (int j = 0; j < 16; ++j) {
        int ir = __builtin_bit_cast(int, v[j].x);
        int ii = __builtin_bit_cast(int, v[j].y);
        ir = __builtin_amdgcn_update_dpp(ir, ir, ctrl, 0xF, BM, false);
        ii = __builtin_amdgcn_update_dpp(ii, ii, ctrl, 0xF, BM, false);
        v[j].x = __builtin_bit_cast(float, ir);
        v[j].y = __builtin_bit_cast(float, ii);
      }
    } else {                          // lane-control, general
      const bool bit = (l & mc) != 0;
      #pragma unroll
      for (int j = 0; j < 16; ++j) {
        v2f x = lanex2<mt>(v[j]);
        v[j] = bit ? x : v[j];
      }
    }
  }
}

// fully unrolled, compile-time op sequence; cacc accumulates the deferred cos factors
template<int K>
__device__ __forceinline__ void apply_ops(v2f (&v)[16], int l, const float* __restrict__ rl, float& cacc) {
  if constexpr (K < NOPS) {
    constexpr int kind = OPS.kind[K];
    if constexpr (kind == 3) {
      g_cnot<OPS.w0[K], OPS.w1[K]>(v, l);
    } else {
      float sn, cs;
      __sincosf(0.5f * rl[K], &sn, &cs);
      const float t = sn * __builtin_amdgcn_rcpf(cs);
      cacc *= cs;
      if constexpr      (kind == 0) g_rx_t<OPS.w0[K]>(v, l, t);
      else if constexpr (kind == 1) g_ry_t<OPS.w0[K]>(v, l, t);
      else                          g_rz_t<OPS.w0[K]>(v, l, t);
    }
    apply_ops<K + 1>(v, l, rl, cacc);
  }
}

// ---- observable: M = nx*X + ny*Y + nz*Z per wire (final RX/RY folded in) ----

template<int M>
__device__ __forceinline__ float xy_inlane(const v2f (&v)[16], float tnx, float tny) {
  v2f aRe = {0.f, 0.f}, aIm = {0.f, 0.f};
  #pragma unroll
  for (int j0 = 0; j0 < 16; ++j0) if ((j0 & M) == 0) {
    const int j1 = j0 | M;
    aRe += v[j0] * v[j1];
    aIm += v[j0] * vswap(v[j1]);
  }
  return tnx * (aRe.x + aRe.y) + tny * (aIm.x - aIm.y);
}

template<int MASK>
__device__ __forceinline__ float xy_cross(const v2f (&v)[16], int l, float nx, float ny) {
  v2f aRe = {0.f, 0.f}, aIm = {0.f, 0.f};
  #pragma unroll
  for (int j = 0; j < 16; ++j) {
    v2f x = lanex2<MASK>(v[j]);
    aRe += v[j] * x;
    aIm += v[j] * vswap(x);
  }
  const float nys = (l & MASK) ? -ny : ny;
  return nx * (aRe.x + aRe.y) + nys * (aIm.x - aIm.y);  // both lanes summed -> factor 2
}

// product-state init for one sample
__device__ __forceinline__ void init_state(v2f (&v)[16], const float* __restrict__ xrow, int l) {
  const float4* xp = reinterpret_cast<const float4*>(xrow);
  const float4 xa = xp[0], xb = xp[1];
  float sw[8], cw[8];
  __sincosf(0.5f * xa.x, &sw[0], &cw[0]);
  __sincosf(0.5f * xa.y, &sw[1], &cw[1]);
  __sincosf(0.5f * xa.z, &sw[2], &cw[2]);
  __sincosf(0.5f * xa.w, &sw[3], &cw[3]);
  __sincosf(0.5f * xb.x, &sw[4], &cw[4]);
  __sincosf(0.5f * xb.y, &sw[5], &cw[5]);
  __sincosf(0.5f * xb.z, &sw[6], &cw[6]);
  __sincosf(0.5f * xb.w, &sw[7], &cw[7]);

  const float pl = ((l & 8) ? sw[4] : cw[4]) * ((l & 4) ? sw[5] : cw[5]) *
                   ((l & 2) ? sw[6] : cw[6]) * ((l & 1) ? sw[7] : cw[7]);
  const float p01[4] = {cw[0]*cw[1], cw[0]*sw[1], sw[0]*cw[1], sw[0]*sw[1]};
  const float p23[4] = {cw[2]*cw[3], cw[2]*sw[3], sw[2]*cw[3], sw[2]*sw[3]};
  const float p01l[4] = {p01[0]*pl, p01[1]*pl, p01[2]*pl, p01[3]*pl};
  #pragma unroll
  for (int j = 0; j < 16; ++j) { v[j].x = p01l[j >> 2] * p23[j & 3]; v[j].y = 0.f; }
}

__global__ __launch_bounds__(256)
void qcnn_kernel(const float* __restrict__ x, const float* __restrict__ rl,
                 const float* __restrict__ thx, const float* __restrict__ thy,
                 float* __restrict__ out)
{
  const int tid = blockIdx.x * blockDim.x + threadIdx.x;
  const int b = tid >> 4;
  const int l = tid & 15;

  v2f v[16];
  init_state(v, x + (size_t)b * 8, l);

  // ---- 20 compile-time gates (tan form, deferred cos product) ----
  float cacc = 1.0f;
  apply_ops<0>(v, l, rl, cacc);
  const float C2 = cacc * cacc;

  // ---- folded final RX/RY layer: observable direction, scaled by C^2 ----
  float sxf, cxf, syf, cyf;
  __sincosf(thx[0], &sxf, &cxf);
  __sincosf(thy[0], &syf, &cyf);
  const float nx = -syf * C2, ny = cyf * sxf * C2, nz = cyf * cxf * C2;
  const float tnx = 2.f * nx, tny = 2.f * ny;

  // ---- Z parts: STREAMING signed |amp|^2 sums (R4 form — q consumed immediately,
  //      5 live v2f accumulators; avoids R9/R10's q[16] register-pressure spike) ----
  v2f P2 = {0,0}, A0v = {0,0}, A1v = {0,0}, A2v = {0,0}, A3v = {0,0};
  #pragma unroll
  for (int j = 0; j < 16; ++j) {
    const v2f q = v[j] * v[j];
    P2 += q;
    if (j & 8) A0v -= q; else A0v += q;
    if (j & 4) A1v -= q; else A1v += q;
    if (j & 2) A2v -= q; else A2v += q;
    if (j & 1) A3v -= q; else A3v += q;
  }
  const float P  = P2.x + P2.y;
  const float A0 = A0v.x + A0v.y, A1 = A1v.x + A1v.y;
  const float A2 = A2v.x + A2v.y, A3 = A3v.x + A3v.y;

  float t0 = fmaf(nz, A0, xy_inlane<8>(v, tnx, tny));
  float t1 = fmaf(nz, A1, xy_inlane<4>(v, tnx, tny));
  float t2 = fmaf(nz, A2, xy_inlane<2>(v, tnx, tny));
  float t3 = fmaf(nz, A3, xy_inlane<1>(v, tnx, tny));
  float t4 = fmaf(nz, (l & 8) ? -P : P, xy_cross<8>(v, l, nx, ny));
  float t5 = fmaf(nz, (l & 4) ? -P : P, xy_cross<4>(v, l, nx, ny));
  float t6 = fmaf(nz, (l & 2) ? -P : P, xy_cross<2>(v, l, nx, ny));
  float t7 = fmaf(nz, (l & 1) ? -P : P, xy_cross<1>(v, l, nx, ny));

  // 16-lane full reduce via {qp_swap1, qp_swap2, ror:4, ror:8} — single-DPP steps
  // (verified R9/R10); after step2 each quad holds its 4-sum, rotations merge all quads.
  #define RED_STEP(CTRL) \
    t0 += lanedpp<CTRL>(t0); t1 += lanedpp<CTRL>(t1); t2 += lanedpp<CTRL>(t2); t3 += lanedpp<CTRL>(t3); \
    t4 += lanedpp<CTRL>(t4); t5 += lanedpp<CTRL>(t5); t6 += lanedpp<CTRL>(t6); t7 += lanedpp<CTRL>(t7);
  RED_STEP(0xB1) RED_STEP(0x4E) RED_STEP(0x124) RED_STEP(0x128)
  #undef RED_STEP

  if (l == 0) {
    float4* o = reinterpret_cast<float4*>(out + (size_t)b * 8);
    const float4 o0 = {t0, t1, t2, t3};
    const float4 o1 = {t4, t5, t6, t7};
    o[0] = o0; o[1] = o1;
  }
}

// ================= host =================

extern "C" void kernel_launch(void* const* d_in, const int* in_sizes, int n_in,
                              void* d_out, int out_size, void* d_ws, size_t ws_size,
                              hipStream_t stream) {
  const float* x   = (const float*)d_in[0];
  const float* rl  = (const float*)d_in[1];
  const float* thx = (const float*)d_in[2];
  const float* thy = (const float*)d_in[3];
  float* out = (float*)d_out;

  const int threads = 256;                  // 4 waves, 16 samples per block
  const int blocks = BSZ / (threads / 16);  // 2048
  qcnn_kernel<<<blocks, threads, 0, stream>>>(x, rl, thx, thy, out);
}

// Round 14
// 27.081 us; speedup vs baseline: 1.0059x; 1.0033x over previous
//
#include <hip/hip_runtime.h>
#include <stdint.h>

#define NQ 8
#define DIM 256
#define BSZ 32768
#define NOPS 20

typedef float v2f __attribute__((ext_vector_type(2)));

// ================= compile-time replication of np.random.RandomState(0) =================

struct COps { int kind[NOPS]; int w0[NOPS]; int w1[NOPS]; };

struct CMT {
  uint32_t mt[624]; int pos;
  constexpr CMT(uint32_t seed) : mt{}, pos(624) {
    for (int i = 0; i < 624; ++i) {
      mt[i] = seed;
      seed = 1812433253u * (seed ^ (seed >> 30)) + (uint32_t)(i + 1);
    }
  }
  constexpr uint32_t next32() {
    if (pos >= 624) {
      for (int i = 0; i < 624; ++i) {
        uint32_t y = (mt[i] & 0x80000000u) | (mt[(i + 1) % 624] & 0x7fffffffu);
        mt[i] = mt[(i + 397) % 624] ^ (y >> 1) ^ ((y & 1u) ? 0x9908b0dfu : 0u);
      }
      pos = 0;
    }
    uint32_t y = mt[pos++];
    y ^= y >> 11; y ^= (y << 7) & 0x9d2c5680u; y ^= (y << 15) & 0xefc60000u; y ^= y >> 18;
    return y;
  }
  constexpr uint32_t interval(uint32_t mx) {  // legacy masked rejection, [0, mx]
    if (mx == 0u) return 0u;
    uint32_t mask = mx;
    mask |= mask >> 1; mask |= mask >> 2; mask |= mask >> 4; mask |= mask >> 8; mask |= mask >> 16;
    uint32_t v = next32() & mask;
    while (v > mx) v = next32() & mask;
    return v;
  }
};

constexpr COps decode_ops() {
  COps o{}; CMT r(0u);
  for (int k = 0; k < NOPS; ++k) {
    const uint32_t kind = r.interval(3u);            // randint(4)
    o.kind[k] = (int)kind;
    if (kind == 3u) {                                // choice(8,2,False) == permutation(8)[:2]
      int perm[NQ] = {0,1,2,3,4,5,6,7};
      for (int i = NQ - 1; i >= 1; --i) {
        const uint32_t j = r.interval((uint32_t)i);
        const int t = perm[i]; perm[i] = perm[(int)j]; perm[(int)j] = t;
      }
      o.w0[k] = perm[0]; o.w1[k] = perm[1];
    } else {
      o.w0[k] = (int)r.interval(7u);                 // randint(8)
      o.w1[k] = -1;
    }
  }
  return o;
}

constexpr COps OPS = decode_ops();

// ================= device helpers =================

// raw-DPP cross-lane read (within 16-lane row)
template<int CTRL>
__device__ __forceinline__ float lanedpp(float v) {
  return __builtin_bit_cast(float,
    __builtin_amdgcn_update_dpp(0, __builtin_bit_cast(int, v), CTRL, 0xF, 0xF, true));
}

// XOR exchange within 16-lane groups — ALL DPP, zero LDS:
//   xor1 = quad_perm(1,0,3,2) 0xB1 ; xor2 = quad_perm(2,3,0,1) 0x4E
//   xor8 = row_ror:8 0x128 ; xor4 = row_half_mirror(xor7) 0x141 + quad_perm(3,2,1,0)(xor3) 0x1B
template<int MASK>
__device__ __forceinline__ float lanexf(float v) {
  if constexpr (MASK == 1)      return lanedpp<0xB1>(v);
  else if constexpr (MASK == 2) return lanedpp<0x4E>(v);
  else if constexpr (MASK == 8) return lanedpp<0x128>(v);
  else                          return lanedpp<0x1B>(lanedpp<0x141>(v));
}

template<int MASK>
__device__ __forceinline__ v2f lanex2(v2f v) {
  v2f r; r.x = lanexf<MASK>(v.x); r.y = lanexf<MASK>(v.y); return r;
}

__device__ __forceinline__ v2f vswap(v2f v) { return __builtin_shufflevector(v, v, 1, 0); }
__device__ __forceinline__ v2f vsplat(float s) { v2f r = {s, s}; return r; }

// Layout: amplitude d = (j<<4)|l ; wire w -> mask m = 1<<(7-w) in d.
// m >= 16: in-lane pair (j0, j0|m>>4) ; m < 16: cross-lane DPP.
// Tan-form gates: U = c(I + t G); c deferred into observable scale C^2.

template<int W>
__device__ __forceinline__ void g_rx_t(v2f (&v)[16], int l, float t) {
  constexpr int m = 1 << (7 - W);
  const v2f tpm = {t, -t};
  if constexpr (m >= 16) {
    constexpr int M = m >> 4;
    #pragma unroll
    for (int j0 = 0; j0 < 16; ++j0) if ((j0 & M) == 0) {
      const int j1 = j0 | M;
      v2f a = v[j0], b = v[j1];
      v[j0] = a + tpm * vswap(b);
      v[j1] = b + tpm * vswap(a);
    }
  } else {
    #pragma unroll
    for (int j = 0; j < 16; ++j) {
      v2f x = lanex2<m>(v[j]);
      v[j] = v[j] + tpm * vswap(x);
    }
  }
}

template<int W>
__device__ __forceinline__ void g_ry_t(v2f (&v)[16], int l, float t) {
  constexpr int m = 1 << (7 - W);
  if constexpr (m >= 16) {
    constexpr int M = m >> 4;
    const v2f vtn = vsplat(-t), vtp = vsplat(t);
    #pragma unroll
    for (int j0 = 0; j0 < 16; ++j0) if ((j0 & M) == 0) {
      const int j1 = j0 | M;
      v2f a = v[j0], b = v[j1];
      v[j0] = a + vtn * b;
      v[j1] = b + vtp * a;
    }
  } else {
    const v2f ts = vsplat((l & m) ? t : -t);
    #pragma unroll
    for (int j = 0; j < 16; ++j) {
      v2f x = lanex2<m>(v[j]);
      v[j] = v[j] + ts * x;
    }
  }
}

template<int W>
__device__ __forceinline__ void g_rz_t(v2f (&v)[16], int l, float t) {
  constexpr int m = 1 << (7 - W);
  if constexpr (m >= 16) {
    constexpr int M = m >> 4;
    const v2f tpm = {t, -t};
    #pragma unroll
    for (int j = 0; j < 16; ++j) {
      v2f sw = vswap(v[j]);
      if ((j & M) == 0) v[j] = v[j] + tpm * sw;
      else              v[j] = v[j] - tpm * sw;
    }
  } else {
    const v2f ts = (l & m) ? (v2f){-t, t} : (v2f){t, -t};
    #pragma unroll
    for (int j = 0; j < 16; ++j) v[j] = v[j] + ts * vswap(v[j]);
  }
}

template<int WC, int WT>
__device__ __forceinline__ void g_cnot(v2f (&v)[16], int l) {
  constexpr int mc = 1 << (7 - WC);
  constexpr int mt = 1 << (7 - WT);
  if constexpr (mt >= 16) {           // in-lane target
    constexpr int M = mt >> 4;
    if constexpr (mc >= 16) {         // j-control: pure register rename
      constexpr int MC = mc >> 4;
      #pragma unroll
      for (int j0 = 0; j0 < 16; ++j0) if ((j0 & M) == 0 && (j0 & MC) != 0) {
        const int j1 = j0 | M;
        v2f t = v[j0]; v[j0] = v[j1]; v[j1] = t;
      }
    } else {                          // lane-control: per-lane select
      const bool bit = (l & mc) != 0;
      #pragma unroll
      for (int j0 = 0; j0 < 16; ++j0) if ((j0 & M) == 0) {
        const int j1 = j0 | M;
        v2f a = v[j0], b = v[j1];
        v[j0] = bit ? b : a;
        v[j1] = bit ? a : b;
      }
    }
  } else {                            // cross-lane target
    if constexpr (mc >= 16) {         // j-control: exchange only controlled j's
      constexpr int MC = mc >> 4;
      #pragma unroll
      for (int j = 0; j < 16; ++j) if (j & MC) v[j] = lanex2<mt>(v[j]);
    } else if constexpr ((mc == 8 || mc == 4) && mt != 4) {
      // lane-control on a bank boundary: bank-masked DPP, no cndmask.
      constexpr int BM   = (mc == 8) ? 0xC : 0xA;
      constexpr int ctrl = (mt == 1) ? 0xB1 : (mt == 2) ? 0x4E : 0x128;
      #pragma unroll
      for (int j = 0; j < 16; ++j) {
        int ir = __builtin_bit_cast(int, v[j].x);
        int ii = __builtin_bit_cast(int, v[j].y);
        ir = __builtin_amdgcn_update_dpp(ir, ir, ctrl, 0xF, BM, false);
        ii = __builtin_amdgcn_update_dpp(ii, ii, ctrl, 0xF, BM, false);
        v[j].x = __builtin_bit_cast(float, ir);
        v[j].y = __builtin_bit_cast(float, ii);
      }
    } else {                          // lane-control, general
      const bool bit = (l & mc) != 0;
      #pragma unroll
      for (int j = 0; j < 16; ++j) {
        v2f x = lanex2<mt>(v[j]);
        v[j] = bit ? x : v[j];
      }
    }
  }
}

// fully unrolled, compile-time op sequence; cacc accumulates the deferred cos factors
template<int K>
__device__ __forceinline__ void apply_ops(v2f (&v)[16], int l, const float* __restrict__ rl, float& cacc) {
  if constexpr (K < NOPS) {
    constexpr int kind = OPS.kind[K];
    if constexpr (kind == 3) {
      g_cnot<OPS.w0[K], OPS.w1[K]>(v, l);
    } else {
      float sn, cs;
      __sincosf(0.5f * rl[K], &sn, &cs);
      const float t = sn * __builtin_amdgcn_rcpf(cs);
      cacc *= cs;
      if constexpr      (kind == 0) g_rx_t<OPS.w0[K]>(v, l, t);
      else if constexpr (kind == 1) g_ry_t<OPS.w0[K]>(v, l, t);
      else                          g_rz_t<OPS.w0[K]>(v, l, t);
    }
    apply_ops<K + 1>(v, l, rl, cacc);
  }
}

// ---- observable: M = nx*X + ny*Y + nz*Z per wire (final RX/RY folded in) ----

template<int M>
__device__ __forceinline__ float xy_inlane(const v2f (&v)[16], float tnx, float tny) {
  v2f aRe = {0.f, 0.f}, aIm = {0.f, 0.f};
  #pragma unroll
  for (int j0 = 0; j0 < 16; ++j0) if ((j0 & M) == 0) {
    const int j1 = j0 | M;
    aRe += v[j0] * v[j1];
    aIm += v[j0] * vswap(v[j1]);
  }
  return tnx * (aRe.x + aRe.y) + tny * (aIm.x - aIm.y);
}

template<int MASK>
__device__ __forceinline__ float xy_cross(const v2f (&v)[16], int l, float nx, float ny) {
  v2f aRe = {0.f, 0.f}, aIm = {0.f, 0.f};
  #pragma unroll
  for (int j = 0; j < 16; ++j) {
    v2f x = lanex2<MASK>(v[j]);
    aRe += v[j] * x;
    aIm += v[j] * vswap(x);
  }
  const float nys = (l & MASK) ? -ny : ny;
  return nx * (aRe.x + aRe.y) + nys * (aIm.x - aIm.y);  // both lanes summed -> factor 2
}

// product-state init for one sample
__device__ __forceinline__ void init_state(v2f (&v)[16], const float* __restrict__ xrow, int l) {
  const float4* xp = reinterpret_cast<const float4*>(xrow);
  const float4 xa = xp[0], xb = xp[1];
  float sw[8], cw[8];
  __sincosf(0.5f * xa.x, &sw[0], &cw[0]);
  __sincosf(0.5f * xa.y, &sw[1], &cw[1]);
  __sincosf(0.5f * xa.z, &sw[2], &cw[2]);
  __sincosf(0.5f * xa.w, &sw[3], &cw[3]);
  __sincosf(0.5f * xb.x, &sw[4], &cw[4]);
  __sincosf(0.5f * xb.y, &sw[5], &cw[5]);
  __sincosf(0.5f * xb.z, &sw[6], &cw[6]);
  __sincosf(0.5f * xb.w, &sw[7], &cw[7]);

  const float pl = ((l & 8) ? sw[4] : cw[4]) * ((l & 4) ? sw[5] : cw[5]) *
                   ((l & 2) ? sw[6] : cw[6]) * ((l & 1) ? sw[7] : cw[7]);
  const float p01[4] = {cw[0]*cw[1], cw[0]*sw[1], sw[0]*cw[1], sw[0]*sw[1]};
  const float p23[4] = {cw[2]*cw[3], cw[2]*sw[3], sw[2]*cw[3], sw[2]*sw[3]};
  const float p01l[4] = {p01[0]*pl, p01[1]*pl, p01[2]*pl, p01[3]*pl};
  #pragma unroll
  for (int j = 0; j < 16; ++j) { v[j].x = p01l[j >> 2] * p23[j & 3]; v[j].y = 0.f; }
}

__global__ __launch_bounds__(256)
void qcnn_kernel(const float* __restrict__ x, const float* __restrict__ rl,
                 const float* __restrict__ thx, const float* __restrict__ thy,
                 float* __restrict__ out)
{
  const int tid = blockIdx.x * blockDim.x + threadIdx.x;
  const int b = tid >> 4;
  const int l = tid & 15;

  v2f v[16];
  init_state(v, x + (size_t)b * 8, l);

  // ---- 20 compile-time gates (tan form, deferred cos product) ----
  float cacc = 1.0f;
  apply_ops<0>(v, l, rl, cacc);
  const float C2 = cacc * cacc;

  // ---- folded final RX/RY layer: observable direction, scaled by C^2 ----
  float sxf, cxf, syf, cyf;
  __sincosf(thx[0], &sxf, &cxf);
  __sincosf(thy[0], &syf, &cyf);
  const float nx = -syf * C2, ny = cyf * sxf * C2, nz = cyf * cxf * C2;
  const float tnx = 2.f * nx, tny = 2.f * ny;

  // ---- Z parts: STREAMING signed |amp|^2 sums (R4 form — q consumed immediately,
  //      5 live v2f accumulators; avoids R9/R10's q[16] register-pressure spike) ----
  v2f P2 = {0,0}, A0v = {0,0}, A1v = {0,0}, A2v = {0,0}, A3v = {0,0};
  #pragma unroll
  for (int j = 0; j < 16; ++j) {
    const v2f q = v[j] * v[j];
    P2 += q;
    if (j & 8) A0v -= q; else A0v += q;
    if (j & 4) A1v -= q; else A1v += q;
    if (j & 2) A2v -= q; else A2v += q;
    if (j & 1) A3v -= q; else A3v += q;
  }
  const float P  = P2.x + P2.y;
  const float A0 = A0v.x + A0v.y, A1 = A1v.x + A1v.y;
  const float A2 = A2v.x + A2v.y, A3 = A3v.x + A3v.y;

  float t0 = fmaf(nz, A0, xy_inlane<8>(v, tnx, tny));
  float t1 = fmaf(nz, A1, xy_inlane<4>(v, tnx, tny));
  float t2 = fmaf(nz, A2, xy_inlane<2>(v, tnx, tny));
  float t3 = fmaf(nz, A3, xy_inlane<1>(v, tnx, tny));
  float t4 = fmaf(nz, (l & 8) ? -P : P, xy_cross<8>(v, l, nx, ny));
  float t5 = fmaf(nz, (l & 4) ? -P : P, xy_cross<4>(v, l, nx, ny));
  float t6 = fmaf(nz, (l & 2) ? -P : P, xy_cross<2>(v, l, nx, ny));
  float t7 = fmaf(nz, (l & 1) ? -P : P, xy_cross<1>(v, l, nx, ny));

  // 16-lane full reduce via {qp_swap1, qp_swap2, ror:4, ror:8} — single-DPP steps
  // (verified R9/R10); after step2 each quad holds its 4-sum, rotations merge all quads.
  #define RED_STEP(CTRL) \
    t0 += lanedpp<CTRL>(t0); t1 += lanedpp<CTRL>(t1); t2 += lanedpp<CTRL>(t2); t3 += lanedpp<CTRL>(t3); \
    t4 += lanedpp<CTRL>(t4); t5 += lanedpp<CTRL>(t5); t6 += lanedpp<CTRL>(t6); t7 += lanedpp<CTRL>(t7);
  RED_STEP(0xB1) RED_STEP(0x4E) RED_STEP(0x124) RED_STEP(0x128)
  #undef RED_STEP

  if (l == 0) {
    float4* o = reinterpret_cast<float4*>(out + (size_t)b * 8);
    const float4 o0 = {t0, t1, t2, t3};
    const float4 o1 = {t4, t5, t6, t7};
    o[0] = o0; o[1] = o1;
  }
}

// ================= host =================

extern "C" void kernel_launch(void* const* d_in, const int* in_sizes, int n_in,
                              void* d_out, int out_size, void* d_ws, size_t ws_size,
                              hipStream_t stream) {
  const float* x   = (const float*)d_in[0];
  const float* rl  = (const float*)d_in[1];
  const float* thx = (const float*)d_in[2];
  const float* thy = (const float*)d_in[3];
  float* out = (float*)d_out;

  const int threads = 256;                  // 4 waves, 16 samples per block
  const int blocks = BSZ / (threads / 16);  // 2048
  qcnn_kernel<<<blocks, threads, 0, stream>>>(x, rl, thx, thy, out);
}

// Round 15
// 23.893 us; speedup vs baseline: 1.1401x; 1.1334x over previous
//
#include <hip/hip_runtime.h>
#include <stdint.h>

#define NQ 8
#define DIM 256
#define BSZ 32768
#define NOPS 20

typedef float v2f __attribute__((ext_vector_type(2)));

// ================= compile-time replication of np.random.RandomState(0) =================

struct COps { int kind[NOPS]; int w0[NOPS]; int w1[NOPS]; };

struct CMT {
  uint32_t mt[624]; int pos;
  constexpr CMT(uint32_t seed) : mt{}, pos(624) {
    for (int i = 0; i < 624; ++i) {
      mt[i] = seed;
      seed = 1812433253u * (seed ^ (seed >> 30)) + (uint32_t)(i + 1);
    }
  }
  constexpr uint32_t next32() {
    if (pos >= 624) {
      for (int i = 0; i < 624; ++i) {
        uint32_t y = (mt[i] & 0x80000000u) | (mt[(i + 1) % 624] & 0x7fffffffu);
        mt[i] = mt[(i + 397) % 624] ^ (y >> 1) ^ ((y & 1u) ? 0x9908b0dfu : 0u);
      }
      pos = 0;
    }
    uint32_t y = mt[pos++];
    y ^= y >> 11; y ^= (y << 7) & 0x9d2c5680u; y ^= (y << 15) & 0xefc60000u; y ^= y >> 18;
    return y;
  }
  constexpr uint32_t interval(uint32_t mx) {  // legacy masked rejection, [0, mx]
    if (mx == 0u) return 0u;
    uint32_t mask = mx;
    mask |= mask >> 1; mask |= mask >> 2; mask |= mask >> 4; mask |= mask >> 8; mask |= mask >> 16;
    uint32_t v = next32() & mask;
    while (v > mx) v = next32() & mask;
    return v;
  }
};

constexpr COps decode_ops() {
  COps o{}; CMT r(0u);
  for (int k = 0; k < NOPS; ++k) {
    const uint32_t kind = r.interval(3u);            // randint(4)
    o.kind[k] = (int)kind;
    if (kind == 3u) {                                // choice(8,2,False) == permutation(8)[:2]
      int perm[NQ] = {0,1,2,3,4,5,6,7};
      for (int i = NQ - 1; i >= 1; --i) {
        const uint32_t j = r.interval((uint32_t)i);
        const int t = perm[i]; perm[i] = perm[(int)j]; perm[(int)j] = t;
      }
      o.w0[k] = perm[0]; o.w1[k] = perm[1];
    } else {
      o.w0[k] = (int)r.interval(7u);                 // randint(8)
      o.w1[k] = -1;
    }
  }
  return o;
}

constexpr COps OPS = decode_ops();

// ================= device helpers =================

// Cross-lane XOR exchange within 16-lane groups.
// masks 1,2,8: DPP (VALU pipe). mask 4: ds_swizzle (LDS pipe, immediate pattern,
// no address VGPR) — deliberately OFFLOADS the bottlenecked VALU pipe; the LDS
// pipe is otherwise idle in this kernel (R4 vs R9/R10/R14 A/B evidence).
template<int MASK>
__device__ __forceinline__ float lanexf(float v) {
  int i = __builtin_bit_cast(int, v);
  int r;
  if constexpr (MASK == 1)      r = __builtin_amdgcn_update_dpp(0, i, 0xB1, 0xF, 0xF, true);  // quad_perm(1,0,3,2)
  else if constexpr (MASK == 2) r = __builtin_amdgcn_update_dpp(0, i, 0x4E, 0xF, 0xF, true);  // quad_perm(2,3,0,1)
  else if constexpr (MASK == 8) r = __builtin_amdgcn_update_dpp(0, i, 0x128, 0xF, 0xF, true); // row_ror:8
  else                          r = __builtin_amdgcn_ds_swizzle(i, 0x101F);                   // xor4
  return __builtin_bit_cast(float, r);
}

template<int MASK>
__device__ __forceinline__ v2f lanex2(v2f v) {
  v2f r; r.x = lanexf<MASK>(v.x); r.y = lanexf<MASK>(v.y); return r;
}

__device__ __forceinline__ v2f vswap(v2f v) { return __builtin_shufflevector(v, v, 1, 0); }
__device__ __forceinline__ v2f vsplat(float s) { v2f r = {s, s}; return r; }

// Layout: amplitude d = (j<<4)|l ; wire w -> mask m = 1<<(7-w) in d.
// m >= 16: in-lane pair (j0, j0|m>>4) ; m < 16: cross-lane via lanex2<m>.
// Tan-form gates: U = c(I + t G); c deferred into observable scale C^2.

template<int W>
__device__ __forceinline__ void g_rx_t(v2f (&v)[16], int l, float t) {
  constexpr int m = 1 << (7 - W);
  const v2f tpm = {t, -t};
  if constexpr (m >= 16) {
    constexpr int M = m >> 4;
    #pragma unroll
    for (int j0 = 0; j0 < 16; ++j0) if ((j0 & M) == 0) {
      const int j1 = j0 | M;
      v2f a = v[j0], b = v[j1];
      v[j0] = a + tpm * vswap(b);   // (r0 + t i1, i0 - t r1)
      v[j1] = b + tpm * vswap(a);
    }
  } else {
    #pragma unroll
    for (int j = 0; j < 16; ++j) {
      v2f x = lanex2<m>(v[j]);
      v[j] = v[j] + tpm * vswap(x);
    }
  }
}

template<int W>
__device__ __forceinline__ void g_ry_t(v2f (&v)[16], int l, float t) {
  constexpr int m = 1 << (7 - W);
  if constexpr (m >= 16) {
    constexpr int M = m >> 4;
    const v2f vtn = vsplat(-t), vtp = vsplat(t);
    #pragma unroll
    for (int j0 = 0; j0 < 16; ++j0) if ((j0 & M) == 0) {
      const int j1 = j0 | M;
      v2f a = v[j0], b = v[j1];
      v[j0] = a + vtn * b;
      v[j1] = b + vtp * a;
    }
  } else {
    const v2f ts = vsplat((l & m) ? t : -t);
    #pragma unroll
    for (int j = 0; j < 16; ++j) {
      v2f x = lanex2<m>(v[j]);
      v[j] = v[j] + ts * x;
    }
  }
}

template<int W>
__device__ __forceinline__ void g_rz_t(v2f (&v)[16], int l, float t) {
  constexpr int m = 1 << (7 - W);
  if constexpr (m >= 16) {
    constexpr int M = m >> 4;
    const v2f tpm = {t, -t};
    #pragma unroll
    for (int j = 0; j < 16; ++j) {
      v2f sw = vswap(v[j]);
      if ((j & M) == 0) v[j] = v[j] + tpm * sw;   // *(1 - i t)
      else              v[j] = v[j] - tpm * sw;   // *(1 + i t)
    }
  } else {
    const v2f ts = (l & m) ? (v2f){-t, t} : (v2f){t, -t};
    #pragma unroll
    for (int j = 0; j < 16; ++j) v[j] = v[j] + ts * vswap(v[j]);
  }
}

template<int WC, int WT>
__device__ __forceinline__ void g_cnot(v2f (&v)[16], int l) {
  constexpr int mc = 1 << (7 - WC);
  constexpr int mt = 1 << (7 - WT);
  if constexpr (mt >= 16) {           // in-lane target
    constexpr int M = mt >> 4;
    if constexpr (mc >= 16) {         // j-control: pure register rename
      constexpr int MC = mc >> 4;
      #pragma unroll
      for (int j0 = 0; j0 < 16; ++j0) if ((j0 & M) == 0 && (j0 & MC) != 0) {
        const int j1 = j0 | M;
        v2f t = v[j0]; v[j0] = v[j1]; v[j1] = t;
      }
    } else {                          // lane-control: per-lane select
      const bool bit = (l & mc) != 0;
      #pragma unroll
      for (int j0 = 0; j0 < 16; ++j0) if ((j0 & M) == 0) {
        const int j1 = j0 | M;
        v2f a = v[j0], b = v[j1];
        v[j0] = bit ? b : a;
        v[j1] = bit ? a : b;
      }
    }
  } else {                            // cross-lane target
    if constexpr (mc >= 16) {         // j-control: exchange only controlled j's
      constexpr int MC = mc >> 4;
      #pragma unroll
      for (int j = 0; j < 16; ++j) if (j & MC) v[j] = lanex2<mt>(v[j]);
    } else if constexpr ((mc == 8 || mc == 4) && mt != 4) {
      // lane-control on a bank boundary: bank-masked DPP, no cndmask.
      constexpr int BM   = (mc == 8) ? 0xC : 0xA;
      constexpr int ctrl = (mt == 1) ? 0xB1 : (mt == 2) ? 0x4E : 0x128;
      #pragma unroll
      for (int j = 0; j < 16; ++j) {
        int ir = __builtin_bit_cast(int, v[j].x);
        int ii = __builtin_bit_cast(int, v[j].y);
        ir = __builtin_amdgcn_update_dpp(ir, ir, ctrl, 0xF, BM, false);
        ii = __builtin_amdgcn_update_dpp(ii, ii, ctrl, 0xF, BM, false);
        v[j].x = __builtin_bit_cast(float, ir);
        v[j].y = __builtin_bit_cast(float, ii);
      }
    } else {                          // lane-control, general
      const bool bit = (l & mc) != 0;
      #pragma unroll
      for (int j = 0; j < 16; ++j) {
        v2f x = lanex2<mt>(v[j]);
        v[j] = bit ? x : v[j];
      }
    }
  }
}

// fully unrolled, compile-time op sequence; cacc accumulates the deferred cos factors
template<int K>
__device__ __forceinline__ void apply_ops(v2f (&v)[16], int l, const float* __restrict__ rl, float& cacc) {
  if constexpr (K < NOPS) {
    constexpr int kind = OPS.kind[K];
    if constexpr (kind == 3) {
      g_cnot<OPS.w0[K], OPS.w1[K]>(v, l);
    } else {
      float sn, cs;
      __sincosf(0.5f * rl[K], &sn, &cs);
      const float t = sn * __builtin_amdgcn_rcpf(cs);
      cacc *= cs;
      if constexpr      (kind == 0) g_rx_t<OPS.w0[K]>(v, l, t);
      else if constexpr (kind == 1) g_ry_t<OPS.w0[K]>(v, l, t);
      else                          g_rz_t<OPS.w0[K]>(v, l, t);
    }
    apply_ops<K + 1>(v, l, rl, cacc);
  }
}

// ---- observable: M = nx*X + ny*Y + nz*Z per wire (final RX/RY folded in) ----

template<int M>
__device__ __forceinline__ float xy_inlane(const v2f (&v)[16], float tnx, float tny) {
  v2f aRe = {0.f, 0.f}, aIm = {0.f, 0.f};
  #pragma unroll
  for (int j0 = 0; j0 < 16; ++j0) if ((j0 & M) == 0) {
    const int j1 = j0 | M;
    aRe += v[j0] * v[j1];
    aIm += v[j0] * vswap(v[j1]);
  }
  return tnx * (aRe.x + aRe.y) + tny * (aIm.x - aIm.y);
}

template<int MASK>
__device__ __forceinline__ float xy_cross(const v2f (&v)[16], int l, float nx, float ny) {
  v2f aRe = {0.f, 0.f}, aIm = {0.f, 0.f};
  #pragma unroll
  for (int j = 0; j < 16; ++j) {
    v2f x = lanex2<MASK>(v[j]);
    aRe += v[j] * x;
    aIm += v[j] * vswap(x);
  }
  const float nys = (l & MASK) ? -ny : ny;
  return nx * (aRe.x + aRe.y) + nys * (aIm.x - aIm.y);  // both lanes summed -> factor 2
}

// product-state init for one sample
__device__ __forceinline__ void init_state(v2f (&v)[16], const float* __restrict__ xrow, int l) {
  const float4* xp = reinterpret_cast<const float4*>(xrow);
  const float4 xa = xp[0], xb = xp[1];
  float sw[8], cw[8];
  __sincosf(0.5f * xa.x, &sw[0], &cw[0]);
  __sincosf(0.5f * xa.y, &sw[1], &cw[1]);
  __sincosf(0.5f * xa.z, &sw[2], &cw[2]);
  __sincosf(0.5f * xa.w, &sw[3], &cw[3]);
  __sincosf(0.5f * xb.x, &sw[4], &cw[4]);
  __sincosf(0.5f * xb.y, &sw[5], &cw[5]);
  __sincosf(0.5f * xb.z, &sw[6], &cw[6]);
  __sincosf(0.5f * xb.w, &sw[7], &cw[7]);

  const float pl = ((l & 8) ? sw[4] : cw[4]) * ((l & 4) ? sw[5] : cw[5]) *
                   ((l & 2) ? sw[6] : cw[6]) * ((l & 1) ? sw[7] : cw[7]);
  const float p01[4] = {cw[0]*cw[1], cw[0]*sw[1], sw[0]*cw[1], sw[0]*sw[1]};
  const float p23[4] = {cw[2]*cw[3], cw[2]*sw[3], sw[2]*cw[3], sw[2]*sw[3]};
  const float p01l[4] = {p01[0]*pl, p01[1]*pl, p01[2]*pl, p01[3]*pl};
  #pragma unroll
  for (int j = 0; j < 16; ++j) { v[j].x = p01l[j >> 2] * p23[j & 3]; v[j].y = 0.f; }
}

__global__ __launch_bounds__(256)
void qcnn_kernel(const float* __restrict__ x, const float* __restrict__ rl,
                 const float* __restrict__ thx, const float* __restrict__ thy,
                 float* __restrict__ out)
{
  const int tid = blockIdx.x * blockDim.x + threadIdx.x;
  const int b = tid >> 4;
  const int l = tid & 15;

  v2f v[16];
  init_state(v, x + (size_t)b * 8, l);

  // ---- 20 compile-time gates (tan form, deferred cos product) ----
  float cacc = 1.0f;
  apply_ops<0>(v, l, rl, cacc);
  const float C2 = cacc * cacc;

  // ---- folded final RX/RY layer: observable direction, scaled by C^2 ----
  float sxf, cxf, syf, cyf;
  __sincosf(thx[0], &sxf, &cxf);
  __sincosf(thy[0], &syf, &cyf);
  const float nx = -syf * C2, ny = cyf * sxf * C2, nz = cyf * cxf * C2;
  const float tnx = 2.f * nx, tny = 2.f * ny;

  // ---- Z parts: streaming signed |amp|^2 sums (5 live accumulators) ----
  v2f P2 = {0,0}, A0v = {0,0}, A1v = {0,0}, A2v = {0,0}, A3v = {0,0};
  #pragma unroll
  for (int j = 0; j < 16; ++j) {
    const v2f q = v[j] * v[j];
    P2 += q;
    if (j & 8) A0v -= q; else A0v += q;
    if (j & 4) A1v -= q; else A1v += q;
    if (j & 2) A2v -= q; else A2v += q;
    if (j & 1) A3v -= q; else A3v += q;
  }
  const float P  = P2.x + P2.y;
  const float A0 = A0v.x + A0v.y, A1 = A1v.x + A1v.y;
  const float A2 = A2v.x + A2v.y, A3 = A3v.x + A3v.y;

  float t0 = fmaf(nz, A0, xy_inlane<8>(v, tnx, tny));
  float t1 = fmaf(nz, A1, xy_inlane<4>(v, tnx, tny));
  float t2 = fmaf(nz, A2, xy_inlane<2>(v, tnx, tny));
  float t3 = fmaf(nz, A3, xy_inlane<1>(v, tnx, tny));
  float t4 = fmaf(nz, (l & 8) ? -P : P, xy_cross<8>(v, l, nx, ny));
  float t5 = fmaf(nz, (l & 4) ? -P : P, xy_cross<4>(v, l, nx, ny));
  float t6 = fmaf(nz, (l & 2) ? -P : P, xy_cross<2>(v, l, nx, ny));
  float t7 = fmaf(nz, (l & 1) ? -P : P, xy_cross<1>(v, l, nx, ny));

  // 16-lane xor-butterfly reduction (mask-4 step rides the LDS pipe via ds_swizzle)
  #define RED_STEP(MK) \
    t0 += lanexf<MK>(t0); t1 += lanexf<MK>(t1); t2 += lanexf<MK>(t2); t3 += lanexf<MK>(t3); \
    t4 += lanexf<MK>(t4); t5 += lanexf<MK>(t5); t6 += lanexf<MK>(t6); t7 += lanexf<MK>(t7);
  RED_STEP(1) RED_STEP(2) RED_STEP(4) RED_STEP(8)
  #undef RED_STEP

  if (l == 0) {
    float4* o = reinterpret_cast<float4*>(out + (size_t)b * 8);
    const float4 o0 = {t0, t1, t2, t3};
    const float4 o1 = {t4, t5, t6, t7};
    o[0] = o0; o[1] = o1;
  }
}

// ================= host =================

extern "C" void kernel_launch(void* const* d_in, const int* in_sizes, int n_in,
                              void* d_out, int out_size, void* d_ws, size_t ws_size,
                              hipStream_t stream) {
  const float* x   = (const float*)d_in[0];
  const float* rl  = (const float*)d_in[1];
  const float* thx = (const float*)d_in[2];
  const float* thy = (const float*)d_in[3];
  float* out = (float*)d_out;

  const int threads = 256;                  // 4 waves, 16 samples per block
  const int blocks = BSZ / (threads / 16);  // 2048
  qcnn_kernel<<<blocks, threads, 0, stream>>>(x, rl, thx, thy, out);
}